// Round 18
// baseline (79.507 us; speedup 1.0000x reference)
//
#include <hip/hip_runtime.h>
#include <hip/hip_bf16.h>
#include <math.h>

#define NB    4
#define NC    128
#define NPIX  3136      // 56*56
#define CHW   401408    // 128*3136
#define SKS   68        // LDS row stride for K/V tiles
#define CTS   19        // conv transpose row stride (odd => bank-clean)

// ---------- DPP wave64 sum (VALU pipe, no DS) ------------------------------
template <int CTRL, int RM>
__device__ __forceinline__ float dpp_mov(float x, float old) {
    return __int_as_float(__builtin_amdgcn_update_dpp(
        __float_as_int(old), __float_as_int(x), CTRL, RM, 0xf, false));
}
__device__ __forceinline__ float wave_sum(float x) {
    x = x + dpp_mov<0x111, 0xf>(x, 0.f);   // row_shr:1
    x = x + dpp_mov<0x112, 0xf>(x, 0.f);   // row_shr:2
    x = x + dpp_mov<0x114, 0xf>(x, 0.f);   // row_shr:4
    x = x + dpp_mov<0x118, 0xf>(x, 0.f);   // row_shr:8
    x = x + dpp_mov<0x142, 0xa>(x, 0.f);   // row_bcast:15 -> rows 1,3
    x = x + dpp_mov<0x143, 0xc>(x, 0.f);   // row_bcast:31 -> rows 2,3
    return __int_as_float(__builtin_amdgcn_readlane(__float_as_int(x), 63));
}

// ---------------- prep: weight pack + rel sums (r7 form) --------------------
__global__ __launch_bounds__(256) void prep_kernel(
    const float* __restrict__ qw, const float* __restrict__ kw,
    const float* __restrict__ vw,
    const float* __restrict__ rel_h, const float* __restrict__ rel_w,
    float* __restrict__ w4q, float* __restrict__ w4k, float* __restrict__ w4v,
    float* __restrict__ rb)
{
    int idx = blockIdx.x * 256 + threadIdx.x;
    if (idx < 3 * 16384) {
        int m = idx >> 14;
        int r = idx & 16383;          // dst-linear: ((c4*128 + o)*4 + cc)
        int cc = r & 3;
        int t = r >> 2;
        int o = t & 127;
        int c4 = t >> 7;
        const float* src = (m == 0) ? qw : (m == 1) ? kw : vw;
        float* dst = (m == 0) ? w4q : (m == 1) ? w4k : w4v;
        dst[r] = src[o * 128 + c4 * 4 + cc];
    }
    if (idx < 14) {
        const float* src = (idx < 7) ? rel_h : rel_w;
        int off = (idx < 7) ? idx : idx - 7;
        float s = 0.f;
        for (int c = 0; c < 64; ++c) s += src[c * 7 + off];
        rb[idx] = s;
    }
}

// ---------------- conv: fused 1x1 convs Q,K,V (fp32, 2-o-per-thread) -------
// 128 threads (2 waves), grid 784. Thread = 8 px x 2 o (ob, ob+64) x 3 mats
// -> 48 accums; per c4-iter 8 batched ds_read_b128 + 6 W4 loads + 192 FMA.
// Total DS instrs HALVED vs r7 (the conv bottleneck per cycle model).
// Single 9.7KB LDS buffer: x-stage region reused as per-mat transpose buf.
__global__ __launch_bounds__(128) void conv_kernel(
    const float* __restrict__ x,
    const float* __restrict__ w4q, const float* __restrict__ w4k,
    const float* __restrict__ w4v,
    const float* __restrict__ qb, const float* __restrict__ kb,
    const float* __restrict__ vb,
    float* __restrict__ q, float* __restrict__ kbuf, float* __restrict__ vbuf)
{
    __shared__ float smem[128 * CTS];    // 9.7KB; [c][16px] during FMA phase
    float* sx = smem;
    int bid = blockIdx.x;
    int tile = bid % 196;
    int b = bid / 196;
    int pix0 = tile * 16;
    const float* xb = x + b * CHW + pix0;

    for (int i = threadIdx.x; i < 512; i += 128) {
        int c = i >> 2, p4 = (i & 3) * 4;
        *(float4*)(sx + c * 16 + p4) = *(const float4*)(xb + c * NPIX + p4);
    }
    __syncthreads();

    int lane = threadIdx.x & 63;
    int wave = threadIdx.x >> 6;
    int ob = wave * 32 + (lane & 31);     // second o = ob + 64
    int ph = (lane >> 5) * 8;
    const float4* Wq = (const float4*)w4q;
    const float4* Wk = (const float4*)w4k;
    const float4* Wv = (const float4*)w4v;

    // depth-1 weight prefetch, 2 o-columns per mat
    float4 wqA = Wq[ob], wqB = Wq[ob + 64];
    float4 wkA = Wk[ob], wkB = Wk[ob + 64];
    float4 wvA = Wv[ob], wvB = Wv[ob + 64];
    float aq0[8] = {}, aq1[8] = {}, ak0[8] = {}, ak1[8] = {};
    float av0[8] = {}, av1[8] = {};
    #pragma unroll 1
    for (int c4 = 0; c4 < 32; ++c4) {
        float4 xs[8];
        #pragma unroll
        for (int cc = 0; cc < 4; ++cc) {
            xs[2 * cc]     = *(const float4*)(sx + (c4 * 4 + cc) * 16 + ph);
            xs[2 * cc + 1] = *(const float4*)(sx + (c4 * 4 + cc) * 16 + ph + 4);
        }
        float4 cqA = wqA, cqB = wqB, ckA = wkA, ckB = wkB, cvA = wvA, cvB = wvB;
        if (c4 < 31) {
            int nx = (c4 + 1) * 128;
            wqA = Wq[nx + ob]; wqB = Wq[nx + ob + 64];
            wkA = Wk[nx + ob]; wkB = Wk[nx + ob + 64];
            wvA = Wv[nx + ob]; wvB = Wv[nx + ob + 64];
        }
        float qA[4] = {cqA.x, cqA.y, cqA.z, cqA.w};
        float qB[4] = {cqB.x, cqB.y, cqB.z, cqB.w};
        float kA[4] = {ckA.x, ckA.y, ckA.z, ckA.w};
        float kB[4] = {ckB.x, ckB.y, ckB.z, ckB.w};
        float vA[4] = {cvA.x, cvA.y, cvA.z, cvA.w};
        float vB[4] = {cvB.x, cvB.y, cvB.z, cvB.w};
        #pragma unroll
        for (int cc = 0; cc < 4; ++cc) {
            float4 xa = xs[2 * cc], xc = xs[2 * cc + 1];
            float xv[8] = {xa.x, xa.y, xa.z, xa.w, xc.x, xc.y, xc.z, xc.w};
            #pragma unroll
            for (int p = 0; p < 8; ++p) {
                aq0[p] += qA[cc] * xv[p];  aq1[p] += qB[cc] * xv[p];
                ak0[p] += kA[cc] * xv[p];  ak1[p] += kB[cc] * xv[p];
                av0[p] += vA[cc] * xv[p];  av1[p] += vB[cc] * xv[p];
            }
        }
    }
    float bq0 = qb[ob], bq1 = qb[ob + 64];
    float bk0 = kb[ob], bk1 = kb[ob + 64];
    float bv0 = vb[ob], bv1 = vb[ob + 64];

    int pix = threadIdx.x & 15;
    int og = threadIdx.x >> 4;            // 0..7, 16 o-rows each
    float* wr0 = smem + ob * CTS + ph;
    float* wr1 = smem + (ob + 64) * CTS + ph;

    // ---- Q ----
    __syncthreads();                      // all sx reads done; reuse smem
    #pragma unroll
    for (int p = 0; p < 8; ++p) { wr0[p] = aq0[p] + bq0; wr1[p] = aq1[p] + bq1; }
    __syncthreads();
    {
        float* qd = q + b * CHW + pix0 + pix;
        #pragma unroll
        for (int i = 0; i < 16; ++i) {
            int r = og * 16 + i;
            qd[r * NPIX] = smem[r * CTS + pix];
        }
    }
    // ---- K ----
    __syncthreads();
    #pragma unroll
    for (int p = 0; p < 8; ++p) { wr0[p] = ak0[p] + bk0; wr1[p] = ak1[p] + bk1; }
    __syncthreads();
    {
        float* kd = kbuf + b * CHW + pix0 + pix;
        #pragma unroll
        for (int i = 0; i < 16; ++i) {
            int r = og * 16 + i;
            kd[r * NPIX] = smem[r * CTS + pix];
        }
    }
    // ---- V ----
    __syncthreads();
    #pragma unroll
    for (int p = 0; p < 8; ++p) { wr0[p] = av0[p] + bv0; wr1[p] = av1[p] + bv1; }
    __syncthreads();
    {
        float* vd = vbuf + b * CHW + pix0 + pix;
        #pragma unroll
        for (int i = 0; i < 16; ++i) {
            int r = og * 16 + i;
            vd[r * NPIX] = smem[r * CTS + pix];
        }
    }
}

// ---------------- attn: r14 verbatim (best measured: ~41 us) ---------------
__global__ __launch_bounds__(256) void attn_kernel(
    const float* __restrict__ q, const float* __restrict__ kbuf,
    const float* __restrict__ vbuf,
    const float* __restrict__ kb, const float* __restrict__ vb,
    const float* __restrict__ rb, float* __restrict__ out)
{
    __shared__ float sK[20 * SKS];
    __shared__ float sV[21 * SKS];   // row 20 zeroed (read only with w=0)
    __shared__ float sW[4 * 64];
    int bid = blockIdx.x;
    int qpart = bid & 3;
    int bc = bid >> 2;
    int ch = bc & 127;
    const float* qc = q + bc * NPIX + 784 * qpart;
    const float* kc = kbuf + bc * NPIX;
    const float* vc = vbuf + bc * NPIX;
    float* oc = out + bc * NPIX + 784 * qpart;
    float kbias = kb[ch], vbias = vb[ch];
    int qr0 = 14 * qpart;

    for (int i = threadIdx.x; i < 20 * 62; i += 256) {
        int yy = i / 62, xx = i - yy * 62;
        int gy = qr0 + yy - 3;
        int gx = xx - 3;
        bool in = (gy >= 0) && (gy < 56) && (gx >= 0) && (gx < 56);
        int off = in ? gy * 56 + gx : 0;
        float kv = in ? kc[off] : kbias;
        float vv = in ? vc[off] : vbias;
        sK[yy * SKS + xx] = kv;
        sV[yy * SKS + xx] = vv;
    }
    for (int i = threadIdx.x; i < SKS; i += 256) sV[20 * SKS + i] = 0.f;

    int lane = threadIdx.x & 63;
    int wave = threadIdx.x >> 6;
    int k2 = min(lane, 48);
    int di = k2 / 7, dj = k2 - di * 7;
    float rbias = rb[di] + rb[7 + dj];
    int koff = di * SKS + dj;
    int t16 = lane & 15, p = lane >> 4;
    float* sWw = sW + wave * 64;

    // uniform rbias extrema (once per block)
    float rhM = rb[0], rhm = rb[0];
    #pragma unroll
    for (int i = 1; i < 7; ++i) { rhM = fmaxf(rhM, rb[i]); rhm = fminf(rhm, rb[i]); }
    float rwM = rb[7], rwm = rb[7];
    #pragma unroll
    for (int i = 8; i < 14; ++i) { rwM = fmaxf(rwM, rb[i]); rwm = fminf(rwm, rb[i]); }
    float rdMax = rbias - (rhM + rwM);   // <= 0 per lane
    float rdMin = rbias - (rhm + rwm);   // >= 0 per lane

    // prefetch first group's q (global loads, no LDS dep -> before barrier)
    int ul0 = wave * 16;               // LOCAL pixel index within quarter
    int y0 = 0, x0 = ul0;
    float4 p0 = *(const float4*)(qc + ul0);
    float4 p1 = *(const float4*)(qc + ul0 + 4);
    float4 p2 = *(const float4*)(qc + ul0 + 8);
    float4 p3 = *(const float4*)(qc + ul0 + 12);
    __syncthreads();

    for (int gl = wave; gl < 49; gl += 4) {
        // --- QK (2 chains) + qs (tree), straight from prefetch regs ------
        float qs = (((p0.x + p0.y) + (p0.z + p0.w)) + ((p1.x + p1.y) + (p1.z + p1.w)))
                 + (((p2.x + p2.y) + (p2.z + p2.w)) + ((p3.x + p3.y) + (p3.z + p3.w)));
        const float* kp = sK + y0 * SKS + x0 + koff;
        int d2 = (x0 == 48) ? (SKS - 48) : 8;          // row-wrap continuation
        const float* kp2 = kp + d2;
        float a0, a1;
        a0  = p0.x * kp[0];   a1  = p0.y * kp[1];
        a0 += p0.z * kp[2];   a1 += p0.w * kp[3];
        a0 += p1.x * kp[4];   a1 += p1.y * kp[5];
        a0 += p1.z * kp[6];   a1 += p1.w * kp[7];
        a0 += p2.x * kp2[0];  a1 += p2.y * kp2[1];
        a0 += p2.z * kp2[2];  a1 += p2.w * kp2[3];
        a0 += p3.x * kp2[4];  a1 += p3.y * kp2[5];
        a0 += p3.z * kp2[6];  a1 += p3.w * kp2[7];
        float acc = a0 + a1;

        // --- reload q regs for group gl+4 (after last use) ---------------
        if (gl + 4 < 49) {
            int un = ul0 + 64;
            p0 = *(const float4*)(qc + un);
            p1 = *(const float4*)(qc + un + 4);
            p2 = *(const float4*)(qc + un + 8);
            p3 = *(const float4*)(qc + un + 12);
        }

        // --- shift-softmax: u = qs*rbsel (uniform) -> no max reduce ------
        float rd = (qs > 0.f) ? rdMax : rdMin;
        float ex = fmaf(qs, rd, acc);
        float e = (lane < 49) ? __expf(ex) : 0.f;
        float sS = wave_sum(e);
        float wgt = e * __builtin_amdgcn_rcpf(sS);
        sWw[lane] = wgt;                               // lanes 49..63 write 0

        // --- PV: lane = (t, ki-row-pair p) -------------------------------
        int u = ul0 + t16;
        int yt = u / 56;
        int xt = u - yt * 56;
        const float* vbase = sV + yt * SKS + xt + p * (2 * SKS);
        const float* wbase = sWw + p * 14;
        float o0 = 0.f, o1 = 0.f;
        #pragma unroll
        for (int j = 0; j < 7; ++j) o0 += wbase[j] * vbase[j];
        #pragma unroll
        for (int j = 0; j < 7; ++j) o1 += wbase[7 + j] * vbase[SKS + j];
        float oacc = o0 + o1;
        oacc += __shfl_xor(oacc, 16);
        oacc += __shfl_xor(oacc, 32);
        if (lane < 16) oc[ul0 + lane] = oacc;

        // advance local coords: ul0 += 64 => y0 += 1, x0 += 8 (with carry)
        ul0 += 64;
        x0 += 8; y0 += 1;
        if (x0 >= 56) { x0 -= 56; ++y0; }
    }
}

extern "C" void kernel_launch(void* const* d_in, const int* in_sizes, int n_in,
                              void* d_out, int out_size, void* d_ws, size_t ws_size,
                              hipStream_t stream) {
    const float* x     = (const float*)d_in[0];
    const float* qw    = (const float*)d_in[1];
    const float* qb    = (const float*)d_in[2];
    const float* kw    = (const float*)d_in[3];
    const float* kb    = (const float*)d_in[4];
    const float* vw    = (const float*)d_in[5];
    const float* vb    = (const float*)d_in[6];
    const float* rel_h = (const float*)d_in[7];
    const float* rel_w = (const float*)d_in[8];
    float* out = (float*)d_out;

    float* ws   = (float*)d_ws;
    float* kbuf = ws;                    // 1605632
    float* vbuf = kbuf + 1605632;        // 1605632
    float* qbuf = vbuf + 1605632;        // 1605632
    float* w4q  = qbuf + 1605632;        // 16384
    float* w4k  = w4q + 16384;
    float* w4v  = w4k + 16384;
    float* rb   = w4v + 16384;           // 16

    prep_kernel<<<192, 256, 0, stream>>>(qw, kw, vw, rel_h, rel_w,
                                         w4q, w4k, w4v, rb);
    conv_kernel<<<784, 128, 0, stream>>>(x, w4q, w4k, w4v, qb, kb, vb,
                                         qbuf, kbuf, vbuf);
    attn_kernel<<<2048, 256, 0, stream>>>(qbuf, kbuf, vbuf, kb, vb, rb, out);
}

// Round 19
// 67.614 us; speedup vs baseline: 1.1759x; 1.1759x over previous
//
#include <hip/hip_runtime.h>
#include <hip/hip_bf16.h>
#include <math.h>

#define NB    4
#define NC    128
#define NPIX  3136      // 56*56
#define CHW   401408    // 128*3136
#define SKS   68        // LDS row stride for K/V tiles

typedef _Float16 f16;
typedef _Float16 f16x8 __attribute__((ext_vector_type(8)));
typedef float f32x4 __attribute__((ext_vector_type(4)));

// ---------- DPP wave64 sum (VALU pipe, no DS) ------------------------------
template <int CTRL, int RM>
__device__ __forceinline__ float dpp_mov(float x, float old) {
    return __int_as_float(__builtin_amdgcn_update_dpp(
        __float_as_int(old), __float_as_int(x), CTRL, RM, 0xf, false));
}
__device__ __forceinline__ float wave_sum(float x) {
    x = x + dpp_mov<0x111, 0xf>(x, 0.f);   // row_shr:1
    x = x + dpp_mov<0x112, 0xf>(x, 0.f);   // row_shr:2
    x = x + dpp_mov<0x114, 0xf>(x, 0.f);   // row_shr:4
    x = x + dpp_mov<0x118, 0xf>(x, 0.f);   // row_shr:8
    x = x + dpp_mov<0x142, 0xa>(x, 0.f);   // row_bcast:15 -> rows 1,3
    x = x + dpp_mov<0x143, 0xc>(x, 0.f);   // row_bcast:31 -> rows 2,3
    return __int_as_float(__builtin_amdgcn_readlane(__float_as_int(x), 63));
}

// ---------------- prep: pack W into MFMA A-fragments (f16 high+low) --------
// Fragment (lane,e) -> A[o = mt*16 + (lane&15)][c = ks*32 + (lane>>4)*4
//                       + (e&3) + (e&4 ? 16 : 0)]
// Linear u16 index: mat*32768 + prec*16384 + mt*2048 + ks*512 + lane*8 + e.
// Same (lane,e)->k map used for B in conv => k-permutation self-consistent.
__global__ __launch_bounds__(256) void prep_kernel(
    const float* __restrict__ qw, const float* __restrict__ kw,
    const float* __restrict__ vw,
    const float* __restrict__ rel_h, const float* __restrict__ rel_w,
    ushort* __restrict__ pk, float* __restrict__ rb)
{
    int idx = blockIdx.x * 256 + threadIdx.x;
    if (idx < 3 * 32768) {
        int e    = idx & 7;
        int l    = (idx >> 3) & 63;
        int ks   = (idx >> 9) & 3;
        int mt   = (idx >> 11) & 7;
        int prec = (idx >> 14) & 1;
        int mat  = idx >> 15;
        int o = mt * 16 + (l & 15);
        int c = ks * 32 + (l >> 4) * 4 + (e & 3) + ((e & 4) ? 16 : 0);
        const float* src = (mat == 0) ? qw : (mat == 1) ? kw : vw;
        float w = src[o * 128 + c];
        f16 wh = (f16)w;
        f16 v = prec ? (f16)(w - (float)wh) : wh;
        ushort u;
        __builtin_memcpy(&u, &v, 2);
        pk[idx] = u;
    }
    if (idx < 14) {
        const float* src = (idx < 7) ? rel_h : rel_w;
        int off = (idx < 7) ? idx : idx - 7;
        float s = 0.f;
        for (int c = 0; c < 64; ++c) s += src[c * 7 + off];
        rb[idx] = s;
    }
}

// ---------------- conv: MFMA split-f16 GEMM, no LDS ------------------------
// block = (b, 16-px tile), 4 waves; wave w owns M-tiles {2w,2w+1} x 3 mats.
// B-frags (x) built in-register (32 coalesced loads + f16 cvt, hi+lo);
// A-frags (W) from prepacked buffer (coalesced dwordx4).
// acc = Wh*xh + Wh*xl + Wl*xh in fp32 (error-compensated f16).
__global__ __launch_bounds__(256) void conv_kernel(
    const float* __restrict__ x, const ushort* __restrict__ pk,
    const float* __restrict__ qb, const float* __restrict__ kb,
    const float* __restrict__ vb,
    float* __restrict__ q, float* __restrict__ kbuf, float* __restrict__ vbuf)
{
    int bid = blockIdx.x;
    int tile = bid % 196;
    int b = bid / 196;
    int pix0 = tile * 16;
    int lane = threadIdx.x & 63;
    int wave = threadIdx.x >> 6;
    int px = lane & 15;
    int lg = lane >> 4;
    const float* xb = x + b * CHW + pix0 + px;

    // B fragments: xh/xl per K-step (k map matches prep's A pack)
    f16x8 bxh[4], bxl[4];
    #pragma unroll
    for (int ks = 0; ks < 4; ++ks) {
        #pragma unroll
        for (int e = 0; e < 8; ++e) {
            int kk = lg * 4 + (e & 3) + ((e & 4) ? 16 : 0);
            float xv = xb[(ks * 32 + kk) * NPIX];
            f16 h = (f16)xv;
            bxh[ks][e] = h;
            bxl[ks][e] = (f16)(xv - (float)h);
        }
    }

    int mtb = wave * 2;
    const f16x8* PK = (const f16x8*)pk;   // frag base: fragid*64 + lane
    #pragma unroll
    for (int mat = 0; mat < 3; ++mat) {
        f32x4 acc0 = {0.f, 0.f, 0.f, 0.f};
        f32x4 acc1 = {0.f, 0.f, 0.f, 0.f};
        #pragma unroll
        for (int ks = 0; ks < 4; ++ks) {
            f16x8 wh0 = PK[(((mat * 2 + 0) * 8 + mtb)     * 4 + ks) * 64 + lane];
            f16x8 wh1 = PK[(((mat * 2 + 0) * 8 + mtb + 1) * 4 + ks) * 64 + lane];
            f16x8 wl0 = PK[(((mat * 2 + 1) * 8 + mtb)     * 4 + ks) * 64 + lane];
            f16x8 wl1 = PK[(((mat * 2 + 1) * 8 + mtb + 1) * 4 + ks) * 64 + lane];
            acc0 = __builtin_amdgcn_mfma_f32_16x16x32_f16(wh0, bxh[ks], acc0, 0, 0, 0);
            acc1 = __builtin_amdgcn_mfma_f32_16x16x32_f16(wh1, bxh[ks], acc1, 0, 0, 0);
            acc0 = __builtin_amdgcn_mfma_f32_16x16x32_f16(wh0, bxl[ks], acc0, 0, 0, 0);
            acc1 = __builtin_amdgcn_mfma_f32_16x16x32_f16(wh1, bxl[ks], acc1, 0, 0, 0);
            acc0 = __builtin_amdgcn_mfma_f32_16x16x32_f16(wl0, bxh[ks], acc0, 0, 0, 0);
            acc1 = __builtin_amdgcn_mfma_f32_16x16x32_f16(wl1, bxh[ks], acc1, 0, 0, 0);
        }
        const float* bias = (mat == 0) ? qb : (mat == 1) ? kb : vb;
        float* dst = ((mat == 0) ? q : (mat == 1) ? kbuf : vbuf)
                     + b * CHW + pix0 + px;
        #pragma unroll
        for (int r = 0; r < 4; ++r) {
            int o0 = mtb * 16 + lg * 4 + r;     // C/D: row=(lane>>4)*4+r
            int o1 = o0 + 16;
            dst[o0 * NPIX] = acc0[r] + bias[o0];
            dst[o1 * NPIX] = acc1[r] + bias[o1];
        }
    }
}

// ---------------- attn: r14 verbatim (best measured) -----------------------
__global__ __launch_bounds__(256) void attn_kernel(
    const float* __restrict__ q, const float* __restrict__ kbuf,
    const float* __restrict__ vbuf,
    const float* __restrict__ kb, const float* __restrict__ vb,
    const float* __restrict__ rb, float* __restrict__ out)
{
    __shared__ float sK[20 * SKS];
    __shared__ float sV[21 * SKS];   // row 20 zeroed (read only with w=0)
    __shared__ float sW[4 * 64];
    int bid = blockIdx.x;
    int qpart = bid & 3;
    int bc = bid >> 2;
    int ch = bc & 127;
    const float* qc = q + bc * NPIX + 784 * qpart;
    const float* kc = kbuf + bc * NPIX;
    const float* vc = vbuf + bc * NPIX;
    float* oc = out + bc * NPIX + 784 * qpart;
    float kbias = kb[ch], vbias = vb[ch];
    int qr0 = 14 * qpart;

    for (int i = threadIdx.x; i < 20 * 62; i += 256) {
        int yy = i / 62, xx = i - yy * 62;
        int gy = qr0 + yy - 3;
        int gx = xx - 3;
        bool in = (gy >= 0) && (gy < 56) && (gx >= 0) && (gx < 56);
        int off = in ? gy * 56 + gx : 0;
        float kv = in ? kc[off] : kbias;
        float vv = in ? vc[off] : vbias;
        sK[yy * SKS + xx] = kv;
        sV[yy * SKS + xx] = vv;
    }
    for (int i = threadIdx.x; i < SKS; i += 256) sV[20 * SKS + i] = 0.f;

    int lane = threadIdx.x & 63;
    int wave = threadIdx.x >> 6;
    int k2 = min(lane, 48);
    int di = k2 / 7, dj = k2 - di * 7;
    float rbias = rb[di] + rb[7 + dj];
    int koff = di * SKS + dj;
    int t16 = lane & 15, p = lane >> 4;
    float* sWw = sW + wave * 64;

    // uniform rbias extrema (once per block)
    float rhM = rb[0], rhm = rb[0];
    #pragma unroll
    for (int i = 1; i < 7; ++i) { rhM = fmaxf(rhM, rb[i]); rhm = fminf(rhm, rb[i]); }
    float rwM = rb[7], rwm = rb[7];
    #pragma unroll
    for (int i = 8; i < 14; ++i) { rwM = fmaxf(rwM, rb[i]); rwm = fminf(rwm, rb[i]); }
    float rdMax = rbias - (rhM + rwM);   // <= 0 per lane
    float rdMin = rbias - (rhm + rwm);   // >= 0 per lane

    // prefetch first group's q (global loads, no LDS dep -> before barrier)
    int ul0 = wave * 16;               // LOCAL pixel index within quarter
    int y0 = 0, x0 = ul0;
    float4 p0 = *(const float4*)(qc + ul0);
    float4 p1 = *(const float4*)(qc + ul0 + 4);
    float4 p2 = *(const float4*)(qc + ul0 + 8);
    float4 p3 = *(const float4*)(qc + ul0 + 12);
    __syncthreads();

    for (int gl = wave; gl < 49; gl += 4) {
        // --- QK (2 chains) + qs (tree), straight from prefetch regs ------
        float qs = (((p0.x + p0.y) + (p0.z + p0.w)) + ((p1.x + p1.y) + (p1.z + p1.w)))
                 + (((p2.x + p2.y) + (p2.z + p2.w)) + ((p3.x + p3.y) + (p3.z + p3.w)));
        const float* kp = sK + y0 * SKS + x0 + koff;
        int d2 = (x0 == 48) ? (SKS - 48) : 8;          // row-wrap continuation
        const float* kp2 = kp + d2;
        float a0, a1;
        a0  = p0.x * kp[0];   a1  = p0.y * kp[1];
        a0 += p0.z * kp[2];   a1 += p0.w * kp[3];
        a0 += p1.x * kp[4];   a1 += p1.y * kp[5];
        a0 += p1.z * kp[6];   a1 += p1.w * kp[7];
        a0 += p2.x * kp2[0];  a1 += p2.y * kp2[1];
        a0 += p2.z * kp2[2];  a1 += p2.w * kp2[3];
        a0 += p3.x * kp2[4];  a1 += p3.y * kp2[5];
        a0 += p3.z * kp2[6];  a1 += p3.w * kp2[7];
        float acc = a0 + a1;

        // --- reload q regs for group gl+4 (after last use) ---------------
        if (gl + 4 < 49) {
            int un = ul0 + 64;
            p0 = *(const float4*)(qc + un);
            p1 = *(const float4*)(qc + un + 4);
            p2 = *(const float4*)(qc + un + 8);
            p3 = *(const float4*)(qc + un + 12);
        }

        // --- shift-softmax: u = qs*rbsel (uniform) -> no max reduce ------
        float rd = (qs > 0.f) ? rdMax : rdMin;
        float ex = fmaf(qs, rd, acc);
        float e = (lane < 49) ? __expf(ex) : 0.f;
        float sS = wave_sum(e);
        float wgt = e * __builtin_amdgcn_rcpf(sS);
        sWw[lane] = wgt;                               // lanes 49..63 write 0

        // --- PV: lane = (t, ki-row-pair p) -------------------------------
        int u = ul0 + t16;
        int yt = u / 56;
        int xt = u - yt * 56;
        const float* vbase = sV + yt * SKS + xt + p * (2 * SKS);
        const float* wbase = sWw + p * 14;
        float o0 = 0.f, o1 = 0.f;
        #pragma unroll
        for (int j = 0; j < 7; ++j) o0 += wbase[j] * vbase[j];
        #pragma unroll
        for (int j = 0; j < 7; ++j) o1 += wbase[7 + j] * vbase[SKS + j];
        float oacc = o0 + o1;
        oacc += __shfl_xor(oacc, 16);
        oacc += __shfl_xor(oacc, 32);
        if (lane < 16) oc[ul0 + lane] = oacc;

        // advance local coords: ul0 += 64 => y0 += 1, x0 += 8 (with carry)
        ul0 += 64;
        x0 += 8; y0 += 1;
        if (x0 >= 56) { x0 -= 56; ++y0; }
    }
}

extern "C" void kernel_launch(void* const* d_in, const int* in_sizes, int n_in,
                              void* d_out, int out_size, void* d_ws, size_t ws_size,
                              hipStream_t stream) {
    const float* x     = (const float*)d_in[0];
    const float* qw    = (const float*)d_in[1];
    const float* qb    = (const float*)d_in[2];
    const float* kw    = (const float*)d_in[3];
    const float* kb    = (const float*)d_in[4];
    const float* vw    = (const float*)d_in[5];
    const float* vb    = (const float*)d_in[6];
    const float* rel_h = (const float*)d_in[7];
    const float* rel_w = (const float*)d_in[8];
    float* out = (float*)d_out;

    float* ws   = (float*)d_ws;
    float* kbuf = ws;                    // 1605632 floats
    float* vbuf = kbuf + 1605632;        // 1605632
    float* qbuf = vbuf + 1605632;        // 1605632
    ushort* pk  = (ushort*)(qbuf + 1605632);   // 98304 u16 (16B-aligned)
    float* rb   = qbuf + 1605632 + 49152;      // 16 floats

    prep_kernel<<<384, 256, 0, stream>>>(qw, kw, vw, rel_h, rel_w, pk, rb);
    conv_kernel<<<784, 256, 0, stream>>>(x, pk, qb, kb, vb,
                                         qbuf, kbuf, vbuf);
    attn_kernel<<<2048, 256, 0, stream>>>(qbuf, kbuf, vbuf, kb, vb, rb, out);
}

// Round 20
// 64.171 us; speedup vs baseline: 1.2390x; 1.0537x over previous
//
#include <hip/hip_runtime.h>
#include <hip/hip_bf16.h>
#include <math.h>

#define NB    4
#define NC    128
#define NPIX  3136      // 56*56
#define CHW   401408    // 128*3136
#define SKS   68        // LDS row stride for K/V tiles

typedef _Float16 f16;
typedef _Float16 f16x8 __attribute__((ext_vector_type(8)));
typedef float f32x4 __attribute__((ext_vector_type(4)));

// ---------- DPP wave64 sum (VALU pipe, no DS) ------------------------------
template <int CTRL, int RM>
__device__ __forceinline__ float dpp_mov(float x, float old) {
    return __int_as_float(__builtin_amdgcn_update_dpp(
        __float_as_int(old), __float_as_int(x), CTRL, RM, 0xf, false));
}
__device__ __forceinline__ float wave_sum(float x) {
    x = x + dpp_mov<0x111, 0xf>(x, 0.f);   // row_shr:1
    x = x + dpp_mov<0x112, 0xf>(x, 0.f);   // row_shr:2
    x = x + dpp_mov<0x114, 0xf>(x, 0.f);   // row_shr:4
    x = x + dpp_mov<0x118, 0xf>(x, 0.f);   // row_shr:8
    x = x + dpp_mov<0x142, 0xa>(x, 0.f);   // row_bcast:15 -> rows 1,3
    x = x + dpp_mov<0x143, 0xc>(x, 0.f);   // row_bcast:31 -> rows 2,3
    return __int_as_float(__builtin_amdgcn_readlane(__float_as_int(x), 63));
}

// ---------------- prep: pack W into MFMA A-fragments (f16 high+low) --------
// k-map (CONTIGUOUS): fragment (lane,e) -> A[o = mt*16 + (lane&15)]
//                                           [c = ks*32 + (lane>>4)*8 + e]
// Same map used for conv's B (x) fragments => contraction-consistent.
// Linear u16 index: mat*32768 + prec*16384 + mt*2048 + ks*512 + lane*8 + e.
__global__ __launch_bounds__(256) void prep_kernel(
    const float* __restrict__ qw, const float* __restrict__ kw,
    const float* __restrict__ vw,
    const float* __restrict__ rel_h, const float* __restrict__ rel_w,
    ushort* __restrict__ pk, float* __restrict__ rb)
{
    int idx = blockIdx.x * 256 + threadIdx.x;
    if (idx < 3 * 32768) {
        int e    = idx & 7;
        int l    = (idx >> 3) & 63;
        int ks   = (idx >> 9) & 3;
        int mt   = (idx >> 11) & 7;
        int prec = (idx >> 14) & 1;
        int mat  = idx >> 15;
        int o = mt * 16 + (l & 15);
        int c = ks * 32 + (l >> 4) * 8 + e;
        const float* src = (mat == 0) ? qw : (mat == 1) ? kw : vw;
        float w = src[o * 128 + c];
        f16 wh = (f16)w;
        f16 v = prec ? (f16)(w - (float)wh) : wh;
        ushort u;
        __builtin_memcpy(&u, &v, 2);
        pk[idx] = u;
    }
    if (idx < 14) {
        const float* src = (idx < 7) ? rel_h : rel_w;
        int off = (idx < 7) ? idx : idx - 7;
        float s = 0.f;
        for (int c = 0; c < 64; ++c) s += src[c * 7 + off];
        rb[idx] = s;
    }
}

// ---------------- conv: MFMA split-f16 GEMM; B-frags via LDS f16 planes ----
// block = (b, 16-px tile), 4 waves; wave w owns M-tiles {2w,2w+1} x 3 mats.
// Stage x once: hi/lo f16 planes [px][c] (stride 136, rows 16B-aligned).
// B-frag set = 8 x ds_read_b128 per lane (k-map matches prep's A pack).
// acc = Wh*xh + Wh*xl + Wl*xh in fp32 (error-compensated f16).
__global__ __launch_bounds__(256) void conv_kernel(
    const float* __restrict__ x, const ushort* __restrict__ pk,
    const float* __restrict__ qb, const float* __restrict__ kb,
    const float* __restrict__ vb,
    float* __restrict__ q, float* __restrict__ kbuf, float* __restrict__ vbuf)
{
    __shared__ __align__(16) ushort sh[16 * 136];   // hi plane [px][c]
    __shared__ __align__(16) ushort sl[16 * 136];   // lo plane [px][c]
    int bid = blockIdx.x;
    int tile = bid % 196;
    int b = bid / 196;
    int pix0 = tile * 16;
    const float* xb = x + b * CHW + pix0;

    {   // stage: thread = (c, px-half); 2 coalesced float4 loads
        int c = threadIdx.x >> 1;
        int px8 = (threadIdx.x & 1) * 8;
        float4 v0 = *(const float4*)(xb + c * NPIX + px8);
        float4 v1 = *(const float4*)(xb + c * NPIX + px8 + 4);
        float vv[8] = {v0.x, v0.y, v0.z, v0.w, v1.x, v1.y, v1.z, v1.w};
        #pragma unroll
        for (int j = 0; j < 8; ++j) {
            f16 h = (f16)vv[j];
            f16 l = (f16)(vv[j] - (float)h);
            ushort uh, ul;
            __builtin_memcpy(&uh, &h, 2);
            __builtin_memcpy(&ul, &l, 2);
            sh[(px8 + j) * 136 + c] = uh;
            sl[(px8 + j) * 136 + c] = ul;
        }
    }
    __syncthreads();

    int lane = threadIdx.x & 63;
    int wave = threadIdx.x >> 6;
    int px = lane & 15;
    int lg = lane >> 4;

    // B fragments: 8 ds_read_b128 total (contiguous k-map)
    f16x8 bxh[4], bxl[4];
    #pragma unroll
    for (int ks = 0; ks < 4; ++ks) {
        bxh[ks] = *(const f16x8*)(sh + px * 136 + ks * 32 + lg * 8);
        bxl[ks] = *(const f16x8*)(sl + px * 136 + ks * 32 + lg * 8);
    }

    int mtb = wave * 2;
    const f16x8* PK = (const f16x8*)pk;   // frag base: fragid*64 + lane
    #pragma unroll
    for (int mat = 0; mat < 3; ++mat) {
        f32x4 acc0 = {0.f, 0.f, 0.f, 0.f};
        f32x4 acc1 = {0.f, 0.f, 0.f, 0.f};
        #pragma unroll
        for (int ks = 0; ks < 4; ++ks) {
            f16x8 wh0 = PK[(((mat * 2 + 0) * 8 + mtb)     * 4 + ks) * 64 + lane];
            f16x8 wh1 = PK[(((mat * 2 + 0) * 8 + mtb + 1) * 4 + ks) * 64 + lane];
            f16x8 wl0 = PK[(((mat * 2 + 1) * 8 + mtb)     * 4 + ks) * 64 + lane];
            f16x8 wl1 = PK[(((mat * 2 + 1) * 8 + mtb + 1) * 4 + ks) * 64 + lane];
            acc0 = __builtin_amdgcn_mfma_f32_16x16x32_f16(wh0, bxh[ks], acc0, 0, 0, 0);
            acc1 = __builtin_amdgcn_mfma_f32_16x16x32_f16(wh1, bxh[ks], acc1, 0, 0, 0);
            acc0 = __builtin_amdgcn_mfma_f32_16x16x32_f16(wh0, bxl[ks], acc0, 0, 0, 0);
            acc1 = __builtin_amdgcn_mfma_f32_16x16x32_f16(wh1, bxl[ks], acc1, 0, 0, 0);
            acc0 = __builtin_amdgcn_mfma_f32_16x16x32_f16(wl0, bxh[ks], acc0, 0, 0, 0);
            acc1 = __builtin_amdgcn_mfma_f32_16x16x32_f16(wl1, bxh[ks], acc1, 0, 0, 0);
        }
        const float* bias = (mat == 0) ? qb : (mat == 1) ? kb : vb;
        float* dst = ((mat == 0) ? q : (mat == 1) ? kbuf : vbuf)
                     + b * CHW + pix0 + px;
        #pragma unroll
        for (int r = 0; r < 4; ++r) {
            int o0 = mtb * 16 + lg * 4 + r;     // C/D: row=(lane>>4)*4+r
            int o1 = o0 + 16;
            dst[o0 * NPIX] = acc0[r] + bias[o0];
            dst[o1 * NPIX] = acc1[r] + bias[o1];
        }
    }
}

// ---------------- attn: r14 verbatim (best measured) -----------------------
__global__ __launch_bounds__(256) void attn_kernel(
    const float* __restrict__ q, const float* __restrict__ kbuf,
    const float* __restrict__ vbuf,
    const float* __restrict__ kb, const float* __restrict__ vb,
    const float* __restrict__ rb, float* __restrict__ out)
{
    __shared__ float sK[20 * SKS];
    __shared__ float sV[21 * SKS];   // row 20 zeroed (read only with w=0)
    __shared__ float sW[4 * 64];
    int bid = blockIdx.x;
    int qpart = bid & 3;
    int bc = bid >> 2;
    int ch = bc & 127;
    const float* qc = q + bc * NPIX + 784 * qpart;
    const float* kc = kbuf + bc * NPIX;
    const float* vc = vbuf + bc * NPIX;
    float* oc = out + bc * NPIX + 784 * qpart;
    float kbias = kb[ch], vbias = vb[ch];
    int qr0 = 14 * qpart;

    for (int i = threadIdx.x; i < 20 * 62; i += 256) {
        int yy = i / 62, xx = i - yy * 62;
        int gy = qr0 + yy - 3;
        int gx = xx - 3;
        bool in = (gy >= 0) && (gy < 56) && (gx >= 0) && (gx < 56);
        int off = in ? gy * 56 + gx : 0;
        float kv = in ? kc[off] : kbias;
        float vv = in ? vc[off] : vbias;
        sK[yy * SKS + xx] = kv;
        sV[yy * SKS + xx] = vv;
    }
    for (int i = threadIdx.x; i < SKS; i += 256) sV[20 * SKS + i] = 0.f;

    int lane = threadIdx.x & 63;
    int wave = threadIdx.x >> 6;
    int k2 = min(lane, 48);
    int di = k2 / 7, dj = k2 - di * 7;
    float rbias = rb[di] + rb[7 + dj];
    int koff = di * SKS + dj;
    int t16 = lane & 15, p = lane >> 4;
    float* sWw = sW + wave * 64;

    // uniform rbias extrema (once per block)
    float rhM = rb[0], rhm = rb[0];
    #pragma unroll
    for (int i = 1; i < 7; ++i) { rhM = fmaxf(rhM, rb[i]); rhm = fminf(rhm, rb[i]); }
    float rwM = rb[7], rwm = rb[7];
    #pragma unroll
    for (int i = 8; i < 14; ++i) { rwM = fmaxf(rwM, rb[i]); rwm = fminf(rwm, rb[i]); }
    float rdMax = rbias - (rhM + rwM);   // <= 0 per lane
    float rdMin = rbias - (rhm + rwm);   // >= 0 per lane

    // prefetch first group's q (global loads, no LDS dep -> before barrier)
    int ul0 = wave * 16;               // LOCAL pixel index within quarter
    int y0 = 0, x0 = ul0;
    float4 p0 = *(const float4*)(qc + ul0);
    float4 p1 = *(const float4*)(qc + ul0 + 4);
    float4 p2 = *(const float4*)(qc + ul0 + 8);
    float4 p3 = *(const float4*)(qc + ul0 + 12);
    __syncthreads();

    for (int gl = wave; gl < 49; gl += 4) {
        // --- QK (2 chains) + qs (tree), straight from prefetch regs ------
        float qs = (((p0.x + p0.y) + (p0.z + p0.w)) + ((p1.x + p1.y) + (p1.z + p1.w)))
                 + (((p2.x + p2.y) + (p2.z + p2.w)) + ((p3.x + p3.y) + (p3.z + p3.w)));
        const float* kp = sK + y0 * SKS + x0 + koff;
        int d2 = (x0 == 48) ? (SKS - 48) : 8;          // row-wrap continuation
        const float* kp2 = kp + d2;
        float a0, a1;
        a0  = p0.x * kp[0];   a1  = p0.y * kp[1];
        a0 += p0.z * kp[2];   a1 += p0.w * kp[3];
        a0 += p1.x * kp[4];   a1 += p1.y * kp[5];
        a0 += p1.z * kp[6];   a1 += p1.w * kp[7];
        a0 += p2.x * kp2[0];  a1 += p2.y * kp2[1];
        a0 += p2.z * kp2[2];  a1 += p2.w * kp2[3];
        a0 += p3.x * kp2[4];  a1 += p3.y * kp2[5];
        a0 += p3.z * kp2[6];  a1 += p3.w * kp2[7];
        float acc = a0 + a1;

        // --- reload q regs for group gl+4 (after last use) ---------------
        if (gl + 4 < 49) {
            int un = ul0 + 64;
            p0 = *(const float4*)(qc + un);
            p1 = *(const float4*)(qc + un + 4);
            p2 = *(const float4*)(qc + un + 8);
            p3 = *(const float4*)(qc + un + 12);
        }

        // --- shift-softmax: u = qs*rbsel (uniform) -> no max reduce ------
        float rd = (qs > 0.f) ? rdMax : rdMin;
        float ex = fmaf(qs, rd, acc);
        float e = (lane < 49) ? __expf(ex) : 0.f;
        float sS = wave_sum(e);
        float wgt = e * __builtin_amdgcn_rcpf(sS);
        sWw[lane] = wgt;                               // lanes 49..63 write 0

        // --- PV: lane = (t, ki-row-pair p) -------------------------------
        int u = ul0 + t16;
        int yt = u / 56;
        int xt = u - yt * 56;
        const float* vbase = sV + yt * SKS + xt + p * (2 * SKS);
        const float* wbase = sWw + p * 14;
        float o0 = 0.f, o1 = 0.f;
        #pragma unroll
        for (int j = 0; j < 7; ++j) o0 += wbase[j] * vbase[j];
        #pragma unroll
        for (int j = 0; j < 7; ++j) o1 += wbase[7 + j] * vbase[SKS + j];
        float oacc = o0 + o1;
        oacc += __shfl_xor(oacc, 16);
        oacc += __shfl_xor(oacc, 32);
        if (lane < 16) oc[ul0 + lane] = oacc;

        // advance local coords: ul0 += 64 => y0 += 1, x0 += 8 (with carry)
        ul0 += 64;
        x0 += 8; y0 += 1;
        if (x0 >= 56) { x0 -= 56; ++y0; }
    }
}

extern "C" void kernel_launch(void* const* d_in, const int* in_sizes, int n_in,
                              void* d_out, int out_size, void* d_ws, size_t ws_size,
                              hipStream_t stream) {
    const float* x     = (const float*)d_in[0];
    const float* qw    = (const float*)d_in[1];
    const float* qb    = (const float*)d_in[2];
    const float* kw    = (const float*)d_in[3];
    const float* kb    = (const float*)d_in[4];
    const float* vw    = (const float*)d_in[5];
    const float* vb    = (const float*)d_in[6];
    const float* rel_h = (const float*)d_in[7];
    const float* rel_w = (const float*)d_in[8];
    float* out = (float*)d_out;

    float* ws   = (float*)d_ws;
    float* kbuf = ws;                    // 1605632 floats
    float* vbuf = kbuf + 1605632;        // 1605632
    float* qbuf = vbuf + 1605632;        // 1605632
    ushort* pk  = (ushort*)(qbuf + 1605632);   // 98304 u16 (16B-aligned)
    float* rb   = qbuf + 1605632 + 49152;      // 16 floats

    prep_kernel<<<384, 256, 0, stream>>>(qw, kw, vw, rel_h, rel_w, pk, rb);
    conv_kernel<<<784, 256, 0, stream>>>(x, pk, qb, kb, vb,
                                         qbuf, kbuf, vbuf);
    attn_kernel<<<2048, 256, 0, stream>>>(qbuf, kbuf, vbuf, kb, vb, rb, out);
}

// Round 21
// 62.816 us; speedup vs baseline: 1.2657x; 1.0216x over previous
//
#include <hip/hip_runtime.h>
#include <hip/hip_bf16.h>
#include <math.h>

#define NB    4
#define NC    128
#define NPIX  3136      // 56*56
#define CHW   401408    // 128*3136
#define SKS   68        // LDS row stride for K/V tiles

typedef _Float16 f16;
typedef _Float16 f16x8 __attribute__((ext_vector_type(8)));
typedef float f32x4 __attribute__((ext_vector_type(4)));

// ---------- DPP wave64 sum (VALU pipe, no DS) ------------------------------
template <int CTRL, int RM>
__device__ __forceinline__ float dpp_mov(float x, float old) {
    return __int_as_float(__builtin_amdgcn_update_dpp(
        __float_as_int(old), __float_as_int(x), CTRL, RM, 0xf, false));
}
__device__ __forceinline__ float wave_sum(float x) {
    x = x + dpp_mov<0x111, 0xf>(x, 0.f);   // row_shr:1
    x = x + dpp_mov<0x112, 0xf>(x, 0.f);   // row_shr:2
    x = x + dpp_mov<0x114, 0xf>(x, 0.f);   // row_shr:4
    x = x + dpp_mov<0x118, 0xf>(x, 0.f);   // row_shr:8
    x = x + dpp_mov<0x142, 0xa>(x, 0.f);   // row_bcast:15 -> rows 1,3
    x = x + dpp_mov<0x143, 0xc>(x, 0.f);   // row_bcast:31 -> rows 2,3
    return __int_as_float(__builtin_amdgcn_readlane(__float_as_int(x), 63));
}

// ---------------- prep: pack W into MFMA A-fragments (f16 high+low) --------
// k-map (CONTIGUOUS): fragment (lane,e) -> A[o = mt*16 + (lane&15)]
//                                           [c = ks*32 + (lane>>4)*8 + e]
// Same map used for conv's B (x) fragments => contraction-consistent.
// Linear u16 index: mat*32768 + prec*16384 + mt*2048 + ks*512 + lane*8 + e.
__global__ __launch_bounds__(256) void prep_kernel(
    const float* __restrict__ qw, const float* __restrict__ kw,
    const float* __restrict__ vw,
    const float* __restrict__ rel_h, const float* __restrict__ rel_w,
    ushort* __restrict__ pk, float* __restrict__ rb)
{
    int idx = blockIdx.x * 256 + threadIdx.x;
    if (idx < 3 * 32768) {
        int e    = idx & 7;
        int l    = (idx >> 3) & 63;
        int ks   = (idx >> 9) & 3;
        int mt   = (idx >> 11) & 7;
        int prec = (idx >> 14) & 1;
        int mat  = idx >> 15;
        int o = mt * 16 + (l & 15);
        int c = ks * 32 + (l >> 4) * 8 + e;
        const float* src = (mat == 0) ? qw : (mat == 1) ? kw : vw;
        float w = src[o * 128 + c];
        f16 wh = (f16)w;
        f16 v = prec ? (f16)(w - (float)wh) : wh;
        ushort u;
        __builtin_memcpy(&u, &v, 2);
        pk[idx] = u;
    }
    if (idx < 14) {
        const float* src = (idx < 7) ? rel_h : rel_w;
        int off = (idx < 7) ? idx : idx - 7;
        float s = 0.f;
        for (int c = 0; c < 64; ++c) s += src[c * 7 + off];
        rb[idx] = s;
    }
}

// ---------------- conv: MFMA split-f16 GEMM, MAT-SPLIT grid ----------------
// block = (b, 16-px tile, mat). grid 2352 (~9 blocks/CU). Wave w owns
// M-tiles {2w, 2w+1} of ONE mat: 16 A-frag loads + 24 MFMA per wave
// (vs 48/72) -> A-load latency hidden by ~8 waves/SIMD occupancy.
// B-frags via LDS f16 hi/lo planes (8 ds_read_b128), re-staged per mat.
__global__ __launch_bounds__(256) void conv_kernel(
    const float* __restrict__ x, const ushort* __restrict__ pk,
    const float* __restrict__ qb, const float* __restrict__ kb,
    const float* __restrict__ vb,
    float* __restrict__ q, float* __restrict__ kbuf, float* __restrict__ vbuf)
{
    __shared__ __align__(16) ushort sh[16 * 136];   // hi plane [px][c]
    __shared__ __align__(16) ushort sl[16 * 136];   // lo plane [px][c]
    int bid = blockIdx.x;
    int mat = bid % 3;
    int t2 = bid / 3;
    int tile = t2 % 196;
    int b = t2 / 196;
    int pix0 = tile * 16;
    const float* xb = x + b * CHW + pix0;

    {   // stage: thread = (c, px-half); 2 coalesced float4 loads
        int c = threadIdx.x >> 1;
        int px8 = (threadIdx.x & 1) * 8;
        float4 v0 = *(const float4*)(xb + c * NPIX + px8);
        float4 v1 = *(const float4*)(xb + c * NPIX + px8 + 4);
        float vv[8] = {v0.x, v0.y, v0.z, v0.w, v1.x, v1.y, v1.z, v1.w};
        #pragma unroll
        for (int j = 0; j < 8; ++j) {
            f16 h = (f16)vv[j];
            f16 l = (f16)(vv[j] - (float)h);
            ushort uh, ul;
            __builtin_memcpy(&uh, &h, 2);
            __builtin_memcpy(&ul, &l, 2);
            sh[(px8 + j) * 136 + c] = uh;
            sl[(px8 + j) * 136 + c] = ul;
        }
    }
    __syncthreads();

    int lane = threadIdx.x & 63;
    int wave = threadIdx.x >> 6;
    int px = lane & 15;
    int lg = lane >> 4;

    // B fragments: 8 ds_read_b128 total (contiguous k-map)
    f16x8 bxh[4], bxl[4];
    #pragma unroll
    for (int ks = 0; ks < 4; ++ks) {
        bxh[ks] = *(const f16x8*)(sh + px * 136 + ks * 32 + lg * 8);
        bxl[ks] = *(const f16x8*)(sl + px * 136 + ks * 32 + lg * 8);
    }

    int mtb = wave * 2;
    const f16x8* PK = (const f16x8*)pk;   // frag base: fragid*64 + lane
    f32x4 acc0 = {0.f, 0.f, 0.f, 0.f};
    f32x4 acc1 = {0.f, 0.f, 0.f, 0.f};
    #pragma unroll
    for (int ks = 0; ks < 4; ++ks) {
        f16x8 wh0 = PK[(((mat * 2 + 0) * 8 + mtb)     * 4 + ks) * 64 + lane];
        f16x8 wh1 = PK[(((mat * 2 + 0) * 8 + mtb + 1) * 4 + ks) * 64 + lane];
        f16x8 wl0 = PK[(((mat * 2 + 1) * 8 + mtb)     * 4 + ks) * 64 + lane];
        f16x8 wl1 = PK[(((mat * 2 + 1) * 8 + mtb + 1) * 4 + ks) * 64 + lane];
        acc0 = __builtin_amdgcn_mfma_f32_16x16x32_f16(wh0, bxh[ks], acc0, 0, 0, 0);
        acc1 = __builtin_amdgcn_mfma_f32_16x16x32_f16(wh1, bxh[ks], acc1, 0, 0, 0);
        acc0 = __builtin_amdgcn_mfma_f32_16x16x32_f16(wh0, bxl[ks], acc0, 0, 0, 0);
        acc1 = __builtin_amdgcn_mfma_f32_16x16x32_f16(wh1, bxl[ks], acc1, 0, 0, 0);
        acc0 = __builtin_amdgcn_mfma_f32_16x16x32_f16(wl0, bxh[ks], acc0, 0, 0, 0);
        acc1 = __builtin_amdgcn_mfma_f32_16x16x32_f16(wl1, bxh[ks], acc1, 0, 0, 0);
    }
    const float* bias = (mat == 0) ? qb : (mat == 1) ? kb : vb;
    float* dst = ((mat == 0) ? q : (mat == 1) ? kbuf : vbuf)
                 + b * CHW + pix0 + px;
    #pragma unroll
    for (int r = 0; r < 4; ++r) {
        int o0 = mtb * 16 + lg * 4 + r;     // C/D: row=(lane>>4)*4+r
        int o1 = o0 + 16;
        dst[o0 * NPIX] = acc0[r] + bias[o0];
        dst[o1 * NPIX] = acc1[r] + bias[o1];
    }
}

// ---------------- attn: r14 verbatim (best measured) -----------------------
__global__ __launch_bounds__(256) void attn_kernel(
    const float* __restrict__ q, const float* __restrict__ kbuf,
    const float* __restrict__ vbuf,
    const float* __restrict__ kb, const float* __restrict__ vb,
    const float* __restrict__ rb, float* __restrict__ out)
{
    __shared__ float sK[20 * SKS];
    __shared__ float sV[21 * SKS];   // row 20 zeroed (read only with w=0)
    __shared__ float sW[4 * 64];
    int bid = blockIdx.x;
    int qpart = bid & 3;
    int bc = bid >> 2;
    int ch = bc & 127;
    const float* qc = q + bc * NPIX + 784 * qpart;
    const float* kc = kbuf + bc * NPIX;
    const float* vc = vbuf + bc * NPIX;
    float* oc = out + bc * NPIX + 784 * qpart;
    float kbias = kb[ch], vbias = vb[ch];
    int qr0 = 14 * qpart;

    for (int i = threadIdx.x; i < 20 * 62; i += 256) {
        int yy = i / 62, xx = i - yy * 62;
        int gy = qr0 + yy - 3;
        int gx = xx - 3;
        bool in = (gy >= 0) && (gy < 56) && (gx >= 0) && (gx < 56);
        int off = in ? gy * 56 + gx : 0;
        float kv = in ? kc[off] : kbias;
        float vv = in ? vc[off] : vbias;
        sK[yy * SKS + xx] = kv;
        sV[yy * SKS + xx] = vv;
    }
    for (int i = threadIdx.x; i < SKS; i += 256) sV[20 * SKS + i] = 0.f;

    int lane = threadIdx.x & 63;
    int wave = threadIdx.x >> 6;
    int k2 = min(lane, 48);
    int di = k2 / 7, dj = k2 - di * 7;
    float rbias = rb[di] + rb[7 + dj];
    int koff = di * SKS + dj;
    int t16 = lane & 15, p = lane >> 4;
    float* sWw = sW + wave * 64;

    // uniform rbias extrema (once per block)
    float rhM = rb[0], rhm = rb[0];
    #pragma unroll
    for (int i = 1; i < 7; ++i) { rhM = fmaxf(rhM, rb[i]); rhm = fminf(rhm, rb[i]); }
    float rwM = rb[7], rwm = rb[7];
    #pragma unroll
    for (int i = 8; i < 14; ++i) { rwM = fmaxf(rwM, rb[i]); rwm = fminf(rwm, rb[i]); }
    float rdMax = rbias - (rhM + rwM);   // <= 0 per lane
    float rdMin = rbias - (rhm + rwm);   // >= 0 per lane

    // prefetch first group's q (global loads, no LDS dep -> before barrier)
    int ul0 = wave * 16;               // LOCAL pixel index within quarter
    int y0 = 0, x0 = ul0;
    float4 p0 = *(const float4*)(qc + ul0);
    float4 p1 = *(const float4*)(qc + ul0 + 4);
    float4 p2 = *(const float4*)(qc + ul0 + 8);
    float4 p3 = *(const float4*)(qc + ul0 + 12);
    __syncthreads();

    for (int gl = wave; gl < 49; gl += 4) {
        // --- QK (2 chains) + qs (tree), straight from prefetch regs ------
        float qs = (((p0.x + p0.y) + (p0.z + p0.w)) + ((p1.x + p1.y) + (p1.z + p1.w)))
                 + (((p2.x + p2.y) + (p2.z + p2.w)) + ((p3.x + p3.y) + (p3.z + p3.w)));
        const float* kp = sK + y0 * SKS + x0 + koff;
        int d2 = (x0 == 48) ? (SKS - 48) : 8;          // row-wrap continuation
        const float* kp2 = kp + d2;
        float a0, a1;
        a0  = p0.x * kp[0];   a1  = p0.y * kp[1];
        a0 += p0.z * kp[2];   a1 += p0.w * kp[3];
        a0 += p1.x * kp[4];   a1 += p1.y * kp[5];
        a0 += p1.z * kp[6];   a1 += p1.w * kp[7];
        a0 += p2.x * kp2[0];  a1 += p2.y * kp2[1];
        a0 += p2.z * kp2[2];  a1 += p2.w * kp2[3];
        a0 += p3.x * kp2[4];  a1 += p3.y * kp2[5];
        a0 += p3.z * kp2[6];  a1 += p3.w * kp2[7];
        float acc = a0 + a1;

        // --- reload q regs for group gl+4 (after last use) ---------------
        if (gl + 4 < 49) {
            int un = ul0 + 64;
            p0 = *(const float4*)(qc + un);
            p1 = *(const float4*)(qc + un + 4);
            p2 = *(const float4*)(qc + un + 8);
            p3 = *(const float4*)(qc + un + 12);
        }

        // --- shift-softmax: u = qs*rbsel (uniform) -> no max reduce ------
        float rd = (qs > 0.f) ? rdMax : rdMin;
        float ex = fmaf(qs, rd, acc);
        float e = (lane < 49) ? __expf(ex) : 0.f;
        float sS = wave_sum(e);
        float wgt = e * __builtin_amdgcn_rcpf(sS);
        sWw[lane] = wgt;                               // lanes 49..63 write 0

        // --- PV: lane = (t, ki-row-pair p) -------------------------------
        int u = ul0 + t16;
        int yt = u / 56;
        int xt = u - yt * 56;
        const float* vbase = sV + yt * SKS + xt + p * (2 * SKS);
        const float* wbase = sWw + p * 14;
        float o0 = 0.f, o1 = 0.f;
        #pragma unroll
        for (int j = 0; j < 7; ++j) o0 += wbase[j] * vbase[j];
        #pragma unroll
        for (int j = 0; j < 7; ++j) o1 += wbase[7 + j] * vbase[SKS + j];
        float oacc = o0 + o1;
        oacc += __shfl_xor(oacc, 16);
        oacc += __shfl_xor(oacc, 32);
        if (lane < 16) oc[ul0 + lane] = oacc;

        // advance local coords: ul0 += 64 => y0 += 1, x0 += 8 (with carry)
        ul0 += 64;
        x0 += 8; y0 += 1;
        if (x0 >= 56) { x0 -= 56; ++y0; }
    }
}

extern "C" void kernel_launch(void* const* d_in, const int* in_sizes, int n_in,
                              void* d_out, int out_size, void* d_ws, size_t ws_size,
                              hipStream_t stream) {
    const float* x     = (const float*)d_in[0];
    const float* qw    = (const float*)d_in[1];
    const float* qb    = (const float*)d_in[2];
    const float* kw    = (const float*)d_in[3];
    const float* kb    = (const float*)d_in[4];
    const float* vw    = (const float*)d_in[5];
    const float* vb    = (const float*)d_in[6];
    const float* rel_h = (const float*)d_in[7];
    const float* rel_w = (const float*)d_in[8];
    float* out = (float*)d_out;

    float* ws   = (float*)d_ws;
    float* kbuf = ws;                    // 1605632 floats
    float* vbuf = kbuf + 1605632;        // 1605632
    float* qbuf = vbuf + 1605632;        // 1605632
    ushort* pk  = (ushort*)(qbuf + 1605632);   // 98304 u16 (16B-aligned)
    float* rb   = qbuf + 1605632 + 49152;      // 16 floats

    prep_kernel<<<384, 256, 0, stream>>>(qw, kw, vw, rel_h, rel_w, pk, rb);
    conv_kernel<<<2352, 256, 0, stream>>>(x, pk, qb, kb, vb,
                                          qbuf, kbuf, vbuf);
    attn_kernel<<<2048, 256, 0, stream>>>(qbuf, kbuf, vbuf, kb, vb, rb, out);
}

// Round 22
// 61.564 us; speedup vs baseline: 1.2914x; 1.0203x over previous
//
#include <hip/hip_runtime.h>
#include <hip/hip_bf16.h>
#include <math.h>

#define NB    4
#define NC    128
#define NPIX  3136      // 56*56
#define CHW   401408    // 128*3136
#define SKS   68        // LDS row stride for K/V tiles

typedef _Float16 f16;
typedef _Float16 f16x8 __attribute__((ext_vector_type(8)));
typedef float f32x4 __attribute__((ext_vector_type(4)));

// ---------- DPP wave64 sum (VALU pipe, no DS) ------------------------------
template <int CTRL, int RM>
__device__ __forceinline__ float dpp_mov(float x, float old) {
    return __int_as_float(__builtin_amdgcn_update_dpp(
        __float_as_int(old), __float_as_int(x), CTRL, RM, 0xf, false));
}
__device__ __forceinline__ float wave_sum(float x) {
    x = x + dpp_mov<0x111, 0xf>(x, 0.f);   // row_shr:1
    x = x + dpp_mov<0x112, 0xf>(x, 0.f);   // row_shr:2
    x = x + dpp_mov<0x114, 0xf>(x, 0.f);   // row_shr:4
    x = x + dpp_mov<0x118, 0xf>(x, 0.f);   // row_shr:8
    x = x + dpp_mov<0x142, 0xa>(x, 0.f);   // row_bcast:15 -> rows 1,3
    x = x + dpp_mov<0x143, 0xc>(x, 0.f);   // row_bcast:31 -> rows 2,3
    return __int_as_float(__builtin_amdgcn_readlane(__float_as_int(x), 63));
}

// ---------------- prep: pack W into MFMA A-fragments (f16 high) ------------
// k-map (CONTIGUOUS): fragment (lane,e) -> A[o = mt*16 + (lane&15)]
//                                           [c = ks*32 + (lane>>4)*8 + e]
// Same map used for conv's B (x) fragments => contraction-consistent.
// Linear u16 index: mat*32768 + prec*16384 + mt*2048 + ks*512 + lane*8 + e.
// (prec=1 lo-residual plane still written; unread by 2-term conv.)
__global__ __launch_bounds__(256) void prep_kernel(
    const float* __restrict__ qw, const float* __restrict__ kw,
    const float* __restrict__ vw,
    const float* __restrict__ rel_h, const float* __restrict__ rel_w,
    ushort* __restrict__ pk, float* __restrict__ rb)
{
    int idx = blockIdx.x * 256 + threadIdx.x;
    if (idx < 3 * 32768) {
        int e    = idx & 7;
        int l    = (idx >> 3) & 63;
        int ks   = (idx >> 9) & 3;
        int mt   = (idx >> 11) & 7;
        int prec = (idx >> 14) & 1;
        int mat  = idx >> 15;
        int o = mt * 16 + (l & 15);
        int c = ks * 32 + (l >> 4) * 8 + e;
        const float* src = (mat == 0) ? qw : (mat == 1) ? kw : vw;
        float w = src[o * 128 + c];
        f16 wh = (f16)w;
        f16 v = prec ? (f16)(w - (float)wh) : wh;
        ushort u;
        __builtin_memcpy(&u, &v, 2);
        pk[idx] = u;
    }
    if (idx < 14) {
        const float* src = (idx < 7) ? rel_h : rel_w;
        int off = (idx < 7) ? idx : idx - 7;
        float s = 0.f;
        for (int c = 0; c < 64; ++c) s += src[c * 7 + off];
        rb[idx] = s;
    }
}

// ---------------- conv: MFMA 2-term f16 GEMM, MAT-SPLIT grid ---------------
// block = (b, 16-px tile, mat). grid 2352. Wave w owns M-tiles {2w,2w+1}.
// acc = Wh*xh + Wh*xl = Wh*x  (W f16-quantized, x exact: predicted
// quantization absmax ~0.046 per r3 calibration). 8 A-loads + 16 MFMA/wave.
__global__ __launch_bounds__(256) void conv_kernel(
    const float* __restrict__ x, const ushort* __restrict__ pk,
    const float* __restrict__ qb, const float* __restrict__ kb,
    const float* __restrict__ vb,
    float* __restrict__ q, float* __restrict__ kbuf, float* __restrict__ vbuf)
{
    __shared__ __align__(16) ushort sh[16 * 136];   // hi plane [px][c]
    __shared__ __align__(16) ushort sl[16 * 136];   // lo plane [px][c]
    int bid = blockIdx.x;
    int mat = bid % 3;
    int t2 = bid / 3;
    int tile = t2 % 196;
    int b = t2 / 196;
    int pix0 = tile * 16;
    const float* xb = x + b * CHW + pix0;

    {   // stage: thread = (c, px-half); 2 coalesced float4 loads
        int c = threadIdx.x >> 1;
        int px8 = (threadIdx.x & 1) * 8;
        float4 v0 = *(const float4*)(xb + c * NPIX + px8);
        float4 v1 = *(const float4*)(xb + c * NPIX + px8 + 4);
        float vv[8] = {v0.x, v0.y, v0.z, v0.w, v1.x, v1.y, v1.z, v1.w};
        #pragma unroll
        for (int j = 0; j < 8; ++j) {
            f16 h = (f16)vv[j];
            f16 l = (f16)(vv[j] - (float)h);
            ushort uh, ul;
            __builtin_memcpy(&uh, &h, 2);
            __builtin_memcpy(&ul, &l, 2);
            sh[(px8 + j) * 136 + c] = uh;
            sl[(px8 + j) * 136 + c] = ul;
        }
    }
    __syncthreads();

    int lane = threadIdx.x & 63;
    int wave = threadIdx.x >> 6;
    int px = lane & 15;
    int lg = lane >> 4;

    // B fragments: 8 ds_read_b128 total (contiguous k-map)
    f16x8 bxh[4], bxl[4];
    #pragma unroll
    for (int ks = 0; ks < 4; ++ks) {
        bxh[ks] = *(const f16x8*)(sh + px * 136 + ks * 32 + lg * 8);
        bxl[ks] = *(const f16x8*)(sl + px * 136 + ks * 32 + lg * 8);
    }

    int mtb = wave * 2;
    const f16x8* PK = (const f16x8*)pk;   // frag base: fragid*64 + lane
    f32x4 acc0 = {0.f, 0.f, 0.f, 0.f};
    f32x4 acc1 = {0.f, 0.f, 0.f, 0.f};
    #pragma unroll
    for (int ks = 0; ks < 4; ++ks) {
        f16x8 wh0 = PK[(((mat * 2 + 0) * 8 + mtb)     * 4 + ks) * 64 + lane];
        f16x8 wh1 = PK[(((mat * 2 + 0) * 8 + mtb + 1) * 4 + ks) * 64 + lane];
        acc0 = __builtin_amdgcn_mfma_f32_16x16x32_f16(wh0, bxh[ks], acc0, 0, 0, 0);
        acc1 = __builtin_amdgcn_mfma_f32_16x16x32_f16(wh1, bxh[ks], acc1, 0, 0, 0);
        acc0 = __builtin_amdgcn_mfma_f32_16x16x32_f16(wh0, bxl[ks], acc0, 0, 0, 0);
        acc1 = __builtin_amdgcn_mfma_f32_16x16x32_f16(wh1, bxl[ks], acc1, 0, 0, 0);
    }
    const float* bias = (mat == 0) ? qb : (mat == 1) ? kb : vb;
    float* dst = ((mat == 0) ? q : (mat == 1) ? kbuf : vbuf)
                 + b * CHW + pix0 + px;
    #pragma unroll
    for (int r = 0; r < 4; ++r) {
        int o0 = mtb * 16 + lg * 4 + r;     // C/D: row=(lane>>4)*4+r
        int o1 = o0 + 16;
        dst[o0 * NPIX] = acc0[r] + bias[o0];
        dst[o1 * NPIX] = acc1[r] + bias[o1];
    }
}

// ---------------- attn: r14 verbatim (best measured) -----------------------
__global__ __launch_bounds__(256) void attn_kernel(
    const float* __restrict__ q, const float* __restrict__ kbuf,
    const float* __restrict__ vbuf,
    const float* __restrict__ kb, const float* __restrict__ vb,
    const float* __restrict__ rb, float* __restrict__ out)
{
    __shared__ float sK[20 * SKS];
    __shared__ float sV[21 * SKS];   // row 20 zeroed (read only with w=0)
    __shared__ float sW[4 * 64];
    int bid = blockIdx.x;
    int qpart = bid & 3;
    int bc = bid >> 2;
    int ch = bc & 127;
    const float* qc = q + bc * NPIX + 784 * qpart;
    const float* kc = kbuf + bc * NPIX;
    const float* vc = vbuf + bc * NPIX;
    float* oc = out + bc * NPIX + 784 * qpart;
    float kbias = kb[ch], vbias = vb[ch];
    int qr0 = 14 * qpart;

    for (int i = threadIdx.x; i < 20 * 62; i += 256) {
        int yy = i / 62, xx = i - yy * 62;
        int gy = qr0 + yy - 3;
        int gx = xx - 3;
        bool in = (gy >= 0) && (gy < 56) && (gx >= 0) && (gx < 56);
        int off = in ? gy * 56 + gx : 0;
        float kv = in ? kc[off] : kbias;
        float vv = in ? vc[off] : vbias;
        sK[yy * SKS + xx] = kv;
        sV[yy * SKS + xx] = vv;
    }
    for (int i = threadIdx.x; i < SKS; i += 256) sV[20 * SKS + i] = 0.f;

    int lane = threadIdx.x & 63;
    int wave = threadIdx.x >> 6;
    int k2 = min(lane, 48);
    int di = k2 / 7, dj = k2 - di * 7;
    float rbias = rb[di] + rb[7 + dj];
    int koff = di * SKS + dj;
    int t16 = lane & 15, p = lane >> 4;
    float* sWw = sW + wave * 64;

    // uniform rbias extrema (once per block)
    float rhM = rb[0], rhm = rb[0];
    #pragma unroll
    for (int i = 1; i < 7; ++i) { rhM = fmaxf(rhM, rb[i]); rhm = fminf(rhm, rb[i]); }
    float rwM = rb[7], rwm = rb[7];
    #pragma unroll
    for (int i = 8; i < 14; ++i) { rwM = fmaxf(rwM, rb[i]); rwm = fminf(rwm, rb[i]); }
    float rdMax = rbias - (rhM + rwM);   // <= 0 per lane
    float rdMin = rbias - (rhm + rwm);   // >= 0 per lane

    // prefetch first group's q (global loads, no LDS dep -> before barrier)
    int ul0 = wave * 16;               // LOCAL pixel index within quarter
    int y0 = 0, x0 = ul0;
    float4 p0 = *(const float4*)(qc + ul0);
    float4 p1 = *(const float4*)(qc + ul0 + 4);
    float4 p2 = *(const float4*)(qc + ul0 + 8);
    float4 p3 = *(const float4*)(qc + ul0 + 12);
    __syncthreads();

    for (int gl = wave; gl < 49; gl += 4) {
        // --- QK (2 chains) + qs (tree), straight from prefetch regs ------
        float qs = (((p0.x + p0.y) + (p0.z + p0.w)) + ((p1.x + p1.y) + (p1.z + p1.w)))
                 + (((p2.x + p2.y) + (p2.z + p2.w)) + ((p3.x + p3.y) + (p3.z + p3.w)));
        const float* kp = sK + y0 * SKS + x0 + koff;
        int d2 = (x0 == 48) ? (SKS - 48) : 8;          // row-wrap continuation
        const float* kp2 = kp + d2;
        float a0, a1;
        a0  = p0.x * kp[0];   a1  = p0.y * kp[1];
        a0 += p0.z * kp[2];   a1 += p0.w * kp[3];
        a0 += p1.x * kp[4];   a1 += p1.y * kp[5];
        a0 += p1.z * kp[6];   a1 += p1.w * kp[7];
        a0 += p2.x * kp2[0];  a1 += p2.y * kp2[1];
        a0 += p2.z * kp2[2];  a1 += p2.w * kp2[3];
        a0 += p3.x * kp2[4];  a1 += p3.y * kp2[5];
        a0 += p3.z * kp2[6];  a1 += p3.w * kp2[7];
        float acc = a0 + a1;

        // --- reload q regs for group gl+4 (after last use) ---------------
        if (gl + 4 < 49) {
            int un = ul0 + 64;
            p0 = *(const float4*)(qc + un);
            p1 = *(const float4*)(qc + un + 4);
            p2 = *(const float4*)(qc + un + 8);
            p3 = *(const float4*)(qc + un + 12);
        }

        // --- shift-softmax: u = qs*rbsel (uniform) -> no max reduce ------
        float rd = (qs > 0.f) ? rdMax : rdMin;
        float ex = fmaf(qs, rd, acc);
        float e = (lane < 49) ? __expf(ex) : 0.f;
        float sS = wave_sum(e);
        float wgt = e * __builtin_amdgcn_rcpf(sS);
        sWw[lane] = wgt;                               // lanes 49..63 write 0

        // --- PV: lane = (t, ki-row-pair p) -------------------------------
        int u = ul0 + t16;
        int yt = u / 56;
        int xt = u - yt * 56;
        const float* vbase = sV + yt * SKS + xt + p * (2 * SKS);
        const float* wbase = sWw + p * 14;
        float o0 = 0.f, o1 = 0.f;
        #pragma unroll
        for (int j = 0; j < 7; ++j) o0 += wbase[j] * vbase[j];
        #pragma unroll
        for (int j = 0; j < 7; ++j) o1 += wbase[7 + j] * vbase[SKS + j];
        float oacc = o0 + o1;
        oacc += __shfl_xor(oacc, 16);
        oacc += __shfl_xor(oacc, 32);
        if (lane < 16) oc[ul0 + lane] = oacc;

        // advance local coords: ul0 += 64 => y0 += 1, x0 += 8 (with carry)
        ul0 += 64;
        x0 += 8; y0 += 1;
        if (x0 >= 56) { x0 -= 56; ++y0; }
    }
}

extern "C" void kernel_launch(void* const* d_in, const int* in_sizes, int n_in,
                              void* d_out, int out_size, void* d_ws, size_t ws_size,
                              hipStream_t stream) {
    const float* x     = (const float*)d_in[0];
    const float* qw    = (const float*)d_in[1];
    const float* qb    = (const float*)d_in[2];
    const float* kw    = (const float*)d_in[3];
    const float* kb    = (const float*)d_in[4];
    const float* vw    = (const float*)d_in[5];
    const float* vb    = (const float*)d_in[6];
    const float* rel_h = (const float*)d_in[7];
    const float* rel_w = (const float*)d_in[8];
    float* out = (float*)d_out;

    float* ws   = (float*)d_ws;
    float* kbuf = ws;                    // 1605632 floats
    float* vbuf = kbuf + 1605632;        // 1605632
    float* qbuf = vbuf + 1605632;        // 1605632
    ushort* pk  = (ushort*)(qbuf + 1605632);   // 98304 u16 (16B-aligned)
    float* rb   = qbuf + 1605632 + 49152;      // 16 floats

    prep_kernel<<<384, 256, 0, stream>>>(qw, kw, vw, rel_h, rel_w, pk, rb);
    conv_kernel<<<2352, 256, 0, stream>>>(x, pk, qb, kb, vb,
                                          qbuf, kbuf, vbuf);
    attn_kernel<<<2048, 256, 0, stream>>>(qbuf, kbuf, vbuf, kb, vb, rb, out);
}